// Round 2
// baseline (4492.219 us; speedup 1.0000x reference)
//
#include <hip/hip_runtime.h>
#include <hip/hip_bf16.h>

#define B_   4
#define L_   2048
#define DM   512
#define DI   1024
#define NST  16
#define DTR  32
#define ROWS (B_ * L_)   // 8192

typedef unsigned short u16;
typedef __attribute__((ext_vector_type(8))) short bf16x8;
typedef __attribute__((ext_vector_type(4))) float f32x4;
typedef __attribute__((ext_vector_type(4))) float float4v;

__device__ __forceinline__ float bf2f(u16 h) {
  union { unsigned int u; float f; } v; v.u = ((unsigned int)h) << 16; return v.f;
}
__device__ __forceinline__ u16 f2bf(float f) {
  union { float f; unsigned int u; } v; v.f = f;
  unsigned int u = v.u;
  if ((u & 0x7fffffffu) > 0x7f800000u) return (u16)((u >> 16) | 0x0040u);
  return (u16)((u + 0x7fffu + ((u >> 16) & 1u)) >> 16);
}
__device__ __forceinline__ float sigmoidf_(float x) { return 1.f / (1.f + __expf(-x)); }

// ---------------- f32 -> bf16 weight conversion ----------------
__global__ __launch_bounds__(256) void cvt_k(const float* __restrict__ in,
                                             u16* __restrict__ out, int n4) {
  int i = blockIdx.x * 256 + threadIdx.x;       // n4 = n/4
  if (i >= n4) return;
  float4v v = *(const float4v*)&in[i * 4];
  u16 o[4];
  o[0] = f2bf(v.x); o[1] = f2bf(v.y); o[2] = f2bf(v.z); o[3] = f2bf(v.w);
  *(ulong1*)&out[i * 4] = *(ulong1*)o;
}

// ---------------- embed gather (writes f32 residual) ----------------
__global__ __launch_bounds__(256) void embed_k(const int* __restrict__ ids,
                                               const float* __restrict__ emb,
                                               float* __restrict__ res, int flip) {
  int idx = blockIdx.x * 256 + threadIdx.x;         // ROWS*DM threads
  int c = idx & (DM - 1);
  int row = idx >> 9;
  int b = row >> 11;
  int l = row & (L_ - 1);
  int sl = flip ? (L_ - 1 - l) : l;
  int id = ids[(b << 11) + sl];
  res[idx] = emb[id * DM + c];
}

// ---------------- (res += hid); xn = rmsnorm(res) * w  (bf16 out) ----------------
template <bool ADD>
__global__ __launch_bounds__(256) void addnorm_k(float* __restrict__ res,
                                                 const float* __restrict__ hid,
                                                 const float* __restrict__ w,
                                                 u16* __restrict__ xn) {
  int row = blockIdx.x;
  int tid = threadIdx.x;
  int base = row * DM;
  float x0 = res[base + tid];
  float x1 = res[base + 256 + tid];
  if (ADD) {
    x0 += hid[base + tid];
    x1 += hid[base + 256 + tid];
    res[base + tid] = x0;
    res[base + 256 + tid] = x1;
  }
  float s = x0 * x0 + x1 * x1;
  for (int off = 32; off; off >>= 1) s += __shfl_xor(s, off);
  __shared__ float ps[4];
  if (!(tid & 63)) ps[tid >> 6] = s;
  __syncthreads();
  float tot = ps[0] + ps[1] + ps[2] + ps[3];
  float rs = 1.f / sqrtf(tot / (float)DM + 1e-5f);
  xn[base + tid]       = f2bf(x0 * rs * w[tid]);
  xn[base + 256 + tid] = f2bf(x1 * rs * w[tid + 256]);
}

// ---------------- GEMM: out[m][n] = sum_k A[m][k] * W[n][k] ----------------
// A: (8192, K) bf16 row-major. W: (N, K) bf16 row-major. Tile 128 x BN, 4 waves 2x2.
template <int BN, bool OUT_BF16, bool HAS_BIAS>
__global__ __launch_bounds__(256) void gemm_bt(const u16* __restrict__ A,
                                               const u16* __restrict__ W,
                                               void* __restrict__ outp,
                                               const float* __restrict__ bias,
                                               int N, int K) {
  constexpr int BM = 128, BK = 32, LDT = BK + 8;   // +8 bf16 pad -> 80B row stride
  constexpr int NF = BN / 32;                      // n-frags per wave
  __shared__ u16 As[BM * LDT];
  __shared__ u16 Wsh[BN * LDT];
  int tid = threadIdx.x;
  int lane = tid & 63;
  int wv = tid >> 6;
  int wr = wv >> 1, wc = wv & 1;
  int m0 = blockIdx.x * BM, n0 = blockIdx.y * BN;
  f32x4 acc[4][NF];
#pragma unroll
  for (int i = 0; i < 4; ++i)
#pragma unroll
    for (int j = 0; j < NF; ++j) acc[i][j] = (f32x4){0.f, 0.f, 0.f, 0.f};
  int rr = lane & 15;
  int kk = (lane >> 4) << 3;
  for (int k0 = 0; k0 < K; k0 += BK) {
#pragma unroll
    for (int p = 0; p < (BM * BK) / 2048; ++p) {
      int idx = p * 2048 + tid * 8;
      int r = idx >> 5, c = idx & 31;
      *(bf16x8*)&As[r * LDT + c] = *(const bf16x8*)&A[(size_t)(m0 + r) * K + k0 + c];
    }
#pragma unroll
    for (int p = 0; p < (BN * BK) / 2048; ++p) {
      int idx = p * 2048 + tid * 8;
      int r = idx >> 5, c = idx & 31;
      *(bf16x8*)&Wsh[r * LDT + c] = *(const bf16x8*)&W[(size_t)(n0 + r) * K + k0 + c];
    }
    __syncthreads();
    bf16x8 af[4], wf[NF];
#pragma unroll
    for (int mi = 0; mi < 4; ++mi)
      af[mi] = *(bf16x8*)&As[(wr * 64 + mi * 16 + rr) * LDT + kk];
#pragma unroll
    for (int ni = 0; ni < NF; ++ni)
      wf[ni] = *(bf16x8*)&Wsh[(wc * (BN / 2) + ni * 16 + rr) * LDT + kk];
#pragma unroll
    for (int mi = 0; mi < 4; ++mi)
#pragma unroll
      for (int ni = 0; ni < NF; ++ni)
        acc[mi][ni] = __builtin_amdgcn_mfma_f32_16x16x32_bf16(af[mi], wf[ni], acc[mi][ni], 0, 0, 0);
    __syncthreads();
  }
  // C/D layout (m89/m91-verified): col = lane&15, row = (lane>>4)*4 + j
  int cr = (lane >> 4) << 2;
  int cc = lane & 15;
#pragma unroll
  for (int mi = 0; mi < 4; ++mi)
#pragma unroll
    for (int ni = 0; ni < NF; ++ni) {
      int row = m0 + wr * 64 + mi * 16 + cr;
      int col = n0 + wc * (BN / 2) + ni * 16 + cc;
      float bv = HAS_BIAS ? bias[col] : 0.f;
#pragma unroll
      for (int j = 0; j < 4; ++j) {
        float v = acc[mi][ni][j] + bv;
        if (OUT_BF16)
          ((u16*)outp)[(size_t)(row + j) * N + col] = f2bf(v);
        else
          ((float*)outp)[(size_t)(row + j) * N + col] = v;
      }
    }
}

// ---------------- depthwise causal conv (k=4) + bias + SiLU ----------------
__global__ __launch_bounds__(256) void conv_k(const u16* __restrict__ xz,
                                              const float* __restrict__ cw,
                                              const float* __restrict__ cb,
                                              float* __restrict__ uf,
                                              u16* __restrict__ uh) {
  int idx = blockIdx.x * 256 + threadIdx.x;        // ROWS*DI
  int c = idx & (DI - 1);
  int row = idx >> 10;
  int l = row & (L_ - 1);
  float acc = cb[c];
#pragma unroll
  for (int j = 0; j < 4; ++j) {
    int ls = l + j - 3;
    if (ls >= 0)
      acc += bf2f(xz[(size_t)(row + j - 3) * (2 * DI) + c]) * cw[c * 4 + j];
  }
  float s = acc * sigmoidf_(acc);
  uf[idx] = s;
  uh[idx] = f2bf(s);
}

// ---------------- dt = softplus(xdbl[:, :32] @ dtw^T + dtb) ----------------
__global__ __launch_bounds__(256) void dtproj_k(const float* __restrict__ xdbl,
                                                const float* __restrict__ dw,
                                                const float* __restrict__ db,
                                                float* __restrict__ dt) {
  int row0 = blockIdx.x * 4;
  int tid = threadIdx.x;
  __shared__ float xr[4 * DTR];
  if (tid < 128) xr[tid] = xdbl[(size_t)(row0 + (tid >> 5)) * 64 + (tid & 31)];
  __syncthreads();
#pragma unroll
  for (int q = 0; q < 4; ++q) {
    int c = q * 256 + tid;
    float wv[DTR];
    const float* wr_ = dw + (size_t)c * DTR;
#pragma unroll
    for (int k = 0; k < DTR; ++k) wv[k] = wr_[k];
    float bias = db[c];
#pragma unroll
    for (int r = 0; r < 4; ++r) {
      float a = bias;
#pragma unroll
      for (int k = 0; k < DTR; ++k) a += xr[r * DTR + k] * wv[k];
      float sp = (a > 20.f) ? a : log1pf(__expf(a));
      dt[(size_t)(row0 + r) * DI + c] = sp;
    }
  }
}

// ---------------- selective scan: 16 lanes per channel, state per lane ----------------
// y may alias u (written after read at same index; same-wave lockstep makes it safe).
__global__ __launch_bounds__(256) void scan_k(const float* u, const float* dt,
                                              const float* __restrict__ xdbl,
                                              const float* __restrict__ alog,
                                              const float* __restrict__ dvec,
                                              float* y) {
  int blk = blockIdx.x;                 // 256 blocks: b(4) x 64 chunks of 16 channels
  int b = blk >> 6;
  int d0 = (blk & 63) << 4;
  int tid = threadIdx.x;
  int g = tid >> 4, n = tid & 15;
  int dd = d0 + g;
  float A = -__expf(alog[dd * NST + n]);
  float Dv = dvec[dd];
  float h = 0.f;
  size_t rbase = ((size_t)b * L_) * DI + dd;
  size_t xbase = ((size_t)b * L_) * 64;
  for (int t = 0; t < L_; ++t) {
    float dtv = dt[rbase];
    float uv = u[rbase];
    float bv = xdbl[xbase + DTR + n];
    float cv = xdbl[xbase + DTR + NST + n];
    h = __expf(dtv * A) * h + (dtv * uv) * bv;
    float p = h * cv;
    p += __shfl_xor(p, 1);
    p += __shfl_xor(p, 2);
    p += __shfl_xor(p, 4);
    p += __shfl_xor(p, 8);
    if (n == 0) y[rbase] = p + uv * Dv;
    rbase += DI;
    xbase += 64;
  }
}

// ---------------- gate: yg = y * silu(z) (bf16 out) ----------------
__global__ __launch_bounds__(256) void gate_k(const float* __restrict__ y,
                                              const u16* __restrict__ xz,
                                              u16* __restrict__ yg) {
  int idx = blockIdx.x * 256 + threadIdx.x;        // ROWS*DI
  int c = idx & (DI - 1);
  int row = idx >> 10;
  float z = bf2f(xz[(size_t)row * (2 * DI) + DI + c]);
  yg[idx] = f2bf(y[idx] * z * sigmoidf_(z));
}

// ---------------- final rmsnorm(hid+res) -> concat buffer (with flip for dir 1) ----------------
__global__ __launch_bounds__(256) void fincat_k(const float* __restrict__ hid,
                                                const float* __restrict__ res,
                                                const float* __restrict__ w,
                                                u16* __restrict__ cat, int dir) {
  int row = blockIdx.x;
  int tid = threadIdx.x;
  int base = row * DM;
  float x0 = hid[base + tid] + res[base + tid];
  float x1 = hid[base + 256 + tid] + res[base + 256 + tid];
  float s = x0 * x0 + x1 * x1;
  for (int off = 32; off; off >>= 1) s += __shfl_xor(s, off);
  __shared__ float ps[4];
  if (!(tid & 63)) ps[tid >> 6] = s;
  __syncthreads();
  float tot = ps[0] + ps[1] + ps[2] + ps[3];
  float rs = 1.f / sqrtf(tot / (float)DM + 1e-5f);
  int b = row >> 11, l = row & (L_ - 1);
  size_t drow = dir ? ((size_t)(b << 11) + (L_ - 1 - l)) : (size_t)row;
  size_t obase = drow * (2 * DM) + (size_t)dir * DM;
  cat[obase + tid]       = f2bf(x0 * rs * w[tid]);
  cat[obase + 256 + tid] = f2bf(x1 * rs * w[tid + 256]);
}

extern "C" void kernel_launch(void* const* d_in, const int* in_sizes, int n_in,
                              void* d_out, int out_size, void* d_ws, size_t ws_size,
                              hipStream_t stream) {
  const int*   ids      = (const int*)d_in[0];
  const float* embed    = (const float*)d_in[2];
  const float* in_w     = (const float*)d_in[3];
  const float* conv_w   = (const float*)d_in[4];
  const float* conv_b   = (const float*)d_in[5];
  const float* x_w      = (const float*)d_in[6];
  const float* dt_w     = (const float*)d_in[7];
  const float* dt_bias  = (const float*)d_in[8];
  const float* A_log    = (const float*)d_in[9];
  const float* Dp       = (const float*)d_in[10];
  const float* out_w    = (const float*)d_in[11];
  const float* norm_w   = (const float*)d_in[12];
  const float* norm_f   = (const float*)d_in[13];
  const float* proj_w   = (const float*)d_in[14];
  const float* proj_b   = (const float*)d_in[15];

  char* ws = (char*)d_ws;
  size_t off = 0;
  auto alloc = [&](size_t bytes) {
    void* p = ws + off;
    off += (bytes + 255) & ~(size_t)255;
    return p;
  };
  float* res  = (float*)alloc((size_t)ROWS * DM * 4);        // 16.8 MB
  float* hid  = (float*)alloc((size_t)ROWS * DM * 4);        // 16.8 MB
  u16*   xnyg = (u16*)alloc((size_t)ROWS * DI * 2);          // 16.8 MB (xn | yg)
  u16*   xz   = (u16*)alloc((size_t)ROWS * 2 * DI * 2);      // 33.6 MB
  float* u_f  = (float*)alloc((size_t)ROWS * DI * 4);        // 33.6 MB (y aliases)
  u16*   u_h  = (u16*)alloc((size_t)ROWS * DI * 2);          // 16.8 MB
  float* xdbl = (float*)alloc((size_t)ROWS * 64 * 4);        //  2.1 MB
  float* dtf  = (float*)alloc((size_t)ROWS * DI * 4);        // 33.6 MB
  u16*   cat  = (u16*)alloc((size_t)ROWS * 2 * DM * 2);      // 16.8 MB
  // bf16 copies of GEMM weights (converted once per launch)
  const int N_IN  = 4 * 2 * DI * DM;   // 4,194,304
  const int N_XW  = 4 * 64 * DI;       //   262,144
  const int N_OW  = 4 * DM * DI;       // 2,097,152
  const int N_PW  = DM * 2 * DM;       //   524,288
  u16* in_wb  = (u16*)alloc((size_t)N_IN * 2);               //  8.4 MB
  u16* x_wb   = (u16*)alloc((size_t)N_XW * 2);               //  0.5 MB
  u16* out_wb = (u16*)alloc((size_t)N_OW * 2);               //  4.2 MB
  u16* pr_wb  = (u16*)alloc((size_t)N_PW * 2);               //  1.0 MB
  if (off > ws_size) return;   // ws too small -> untouched output (diagnosable)

  cvt_k<<<(N_IN / 4 + 255) / 256, 256, 0, stream>>>(in_w, in_wb, N_IN / 4);
  cvt_k<<<(N_XW / 4 + 255) / 256, 256, 0, stream>>>(x_w, x_wb, N_XW / 4);
  cvt_k<<<(N_OW / 4 + 255) / 256, 256, 0, stream>>>(out_w, out_wb, N_OW / 4);
  cvt_k<<<(N_PW / 4 + 255) / 256, 256, 0, stream>>>(proj_w, pr_wb, N_PW / 4);

  for (int d = 0; d < 2; ++d) {
    embed_k<<<ROWS * DM / 256, 256, 0, stream>>>(ids, embed + (size_t)d * 128 * DM, res, d);
    for (int i = 0; i < 2; ++i) {
      int li = d * 2 + i;
      if (i == 0)
        addnorm_k<false><<<ROWS, 256, 0, stream>>>(res, hid, norm_w + (size_t)li * DM, xnyg);
      else
        addnorm_k<true><<<ROWS, 256, 0, stream>>>(res, hid, norm_w + (size_t)li * DM, xnyg);
      gemm_bt<128, true, false><<<dim3(ROWS / 128, 2 * DI / 128), 256, 0, stream>>>(
          xnyg, in_wb + (size_t)li * 2 * DI * DM, xz, nullptr, 2 * DI, DM);
      conv_k<<<ROWS * DI / 256, 256, 0, stream>>>(
          xz, conv_w + (size_t)li * DI * 4, conv_b + (size_t)li * DI, u_f, u_h);
      gemm_bt<64, false, false><<<dim3(ROWS / 128, 1), 256, 0, stream>>>(
          u_h, x_wb + (size_t)li * 64 * DI, xdbl, nullptr, 64, DI);
      dtproj_k<<<ROWS / 4, 256, 0, stream>>>(
          xdbl, dt_w + (size_t)li * DI * DTR, dt_bias + (size_t)li * DI, dtf);
      scan_k<<<256, 256, 0, stream>>>(
          u_f, dtf, xdbl, A_log + (size_t)li * DI * NST, Dp + (size_t)li * DI, u_f);
      gate_k<<<ROWS * DI / 256, 256, 0, stream>>>(u_f, xz, xnyg);
      gemm_bt<128, false, false><<<dim3(ROWS / 128, DM / 128), 256, 0, stream>>>(
          xnyg, out_wb + (size_t)li * DM * DI, hid, nullptr, DM, DI);
    }
    fincat_k<<<ROWS, 256, 0, stream>>>(hid, res, norm_f + (size_t)d * DM, cat, d);
  }
  gemm_bt<128, false, true><<<dim3(ROWS / 128, DM / 128), 256, 0, stream>>>(
      cat, pr_wb, (float*)d_out, proj_b, DM, DI);
}

// Round 3
// 1543.696 us; speedup vs baseline: 2.9100x; 2.9100x over previous
//
#include <hip/hip_runtime.h>
#include <hip/hip_bf16.h>

#define B_   4
#define L_   2048
#define DM   512
#define DI   1024
#define NST  16
#define DTR  32
#define ROWS (B_ * L_)   // 8192
#define NCHUNK 32
#define CLEN  (L_ / NCHUNK)   // 64

typedef unsigned short u16;
typedef __attribute__((ext_vector_type(8))) short bf16x8;
typedef __attribute__((ext_vector_type(4))) float f32x4;
typedef __attribute__((ext_vector_type(4))) float float4v;

__device__ __forceinline__ float bf2f(u16 h) {
  union { unsigned int u; float f; } v; v.u = ((unsigned int)h) << 16; return v.f;
}
__device__ __forceinline__ u16 f2bf(float f) {
  union { float f; unsigned int u; } v; v.f = f;
  unsigned int u = v.u;
  if ((u & 0x7fffffffu) > 0x7f800000u) return (u16)((u >> 16) | 0x0040u);
  return (u16)((u + 0x7fffu + ((u >> 16) & 1u)) >> 16);
}
__device__ __forceinline__ float sigmoidf_(float x) { return 1.f / (1.f + __expf(-x)); }

// ---------------- f32 -> bf16 weight conversion ----------------
__global__ __launch_bounds__(256) void cvt_k(const float* __restrict__ in,
                                             u16* __restrict__ out, int n4) {
  int i = blockIdx.x * 256 + threadIdx.x;       // n4 = n/4
  if (i >= n4) return;
  float4v v = *(const float4v*)&in[i * 4];
  u16 o[4];
  o[0] = f2bf(v.x); o[1] = f2bf(v.y); o[2] = f2bf(v.z); o[3] = f2bf(v.w);
  *(ulong1*)&out[i * 4] = *(ulong1*)o;
}

// ---------------- embed gather (writes f32 residual) ----------------
__global__ __launch_bounds__(256) void embed_k(const int* __restrict__ ids,
                                               const float* __restrict__ emb,
                                               float* __restrict__ res, int flip) {
  int idx = blockIdx.x * 256 + threadIdx.x;         // ROWS*DM threads
  int c = idx & (DM - 1);
  int row = idx >> 9;
  int b = row >> 11;
  int l = row & (L_ - 1);
  int sl = flip ? (L_ - 1 - l) : l;
  int id = ids[(b << 11) + sl];
  res[idx] = emb[id * DM + c];
}

// ---------------- (res += hid); xn = rmsnorm(res) * w  (bf16 out) ----------------
template <bool ADD>
__global__ __launch_bounds__(256) void addnorm_k(float* __restrict__ res,
                                                 const float* __restrict__ hid,
                                                 const float* __restrict__ w,
                                                 u16* __restrict__ xn) {
  int row = blockIdx.x;
  int tid = threadIdx.x;
  int base = row * DM;
  float x0 = res[base + tid];
  float x1 = res[base + 256 + tid];
  if (ADD) {
    x0 += hid[base + tid];
    x1 += hid[base + 256 + tid];
    res[base + tid] = x0;
    res[base + 256 + tid] = x1;
  }
  float s = x0 * x0 + x1 * x1;
  for (int off = 32; off; off >>= 1) s += __shfl_xor(s, off);
  __shared__ float ps[4];
  if (!(tid & 63)) ps[tid >> 6] = s;
  __syncthreads();
  float tot = ps[0] + ps[1] + ps[2] + ps[3];
  float rs = 1.f / sqrtf(tot / (float)DM + 1e-5f);
  xn[base + tid]       = f2bf(x0 * rs * w[tid]);
  xn[base + 256 + tid] = f2bf(x1 * rs * w[tid + 256]);
}

// ---------------- GEMM: out[m][n] = sum_k A[m][k] * W[n][k] ----------------
template <int BN, bool OUT_BF16, bool HAS_BIAS>
__global__ __launch_bounds__(256) void gemm_bt(const u16* __restrict__ A,
                                               const u16* __restrict__ W,
                                               void* __restrict__ outp,
                                               const float* __restrict__ bias,
                                               int N, int K) {
  constexpr int BM = 128, BK = 32, LDT = BK + 8;   // +8 bf16 pad -> 80B row stride
  constexpr int NF = BN / 32;                      // n-frags per wave
  __shared__ u16 As[BM * LDT];
  __shared__ u16 Wsh[BN * LDT];
  int tid = threadIdx.x;
  int lane = tid & 63;
  int wv = tid >> 6;
  int wr = wv >> 1, wc = wv & 1;
  int m0 = blockIdx.x * BM, n0 = blockIdx.y * BN;
  f32x4 acc[4][NF];
#pragma unroll
  for (int i = 0; i < 4; ++i)
#pragma unroll
    for (int j = 0; j < NF; ++j) acc[i][j] = (f32x4){0.f, 0.f, 0.f, 0.f};
  int rr = lane & 15;
  int kk = (lane >> 4) << 3;
  for (int k0 = 0; k0 < K; k0 += BK) {
#pragma unroll
    for (int p = 0; p < (BM * BK) / 2048; ++p) {
      int idx = p * 2048 + tid * 8;
      int r = idx >> 5, c = idx & 31;
      *(bf16x8*)&As[r * LDT + c] = *(const bf16x8*)&A[(size_t)(m0 + r) * K + k0 + c];
    }
#pragma unroll
    for (int p = 0; p < (BN * BK) / 2048; ++p) {
      int idx = p * 2048 + tid * 8;
      int r = idx >> 5, c = idx & 31;
      *(bf16x8*)&Wsh[r * LDT + c] = *(const bf16x8*)&W[(size_t)(n0 + r) * K + k0 + c];
    }
    __syncthreads();
    bf16x8 af[4], wf[NF];
#pragma unroll
    for (int mi = 0; mi < 4; ++mi)
      af[mi] = *(bf16x8*)&As[(wr * 64 + mi * 16 + rr) * LDT + kk];
#pragma unroll
    for (int ni = 0; ni < NF; ++ni)
      wf[ni] = *(bf16x8*)&Wsh[(wc * (BN / 2) + ni * 16 + rr) * LDT + kk];
#pragma unroll
    for (int mi = 0; mi < 4; ++mi)
#pragma unroll
      for (int ni = 0; ni < NF; ++ni)
        acc[mi][ni] = __builtin_amdgcn_mfma_f32_16x16x32_bf16(af[mi], wf[ni], acc[mi][ni], 0, 0, 0);
    __syncthreads();
  }
  // C/D layout: col = lane&15, row = (lane>>4)*4 + j
  int cr = (lane >> 4) << 2;
  int cc = lane & 15;
#pragma unroll
  for (int mi = 0; mi < 4; ++mi)
#pragma unroll
    for (int ni = 0; ni < NF; ++ni) {
      int row = m0 + wr * 64 + mi * 16 + cr;
      int col = n0 + wc * (BN / 2) + ni * 16 + cc;
      float bv = HAS_BIAS ? bias[col] : 0.f;
#pragma unroll
      for (int j = 0; j < 4; ++j) {
        float v = acc[mi][ni][j] + bv;
        if (OUT_BF16)
          ((u16*)outp)[(size_t)(row + j) * N + col] = f2bf(v);
        else
          ((float*)outp)[(size_t)(row + j) * N + col] = v;
      }
    }
}

// ---------------- depthwise causal conv (k=4) + bias + SiLU ----------------
__global__ __launch_bounds__(256) void conv_k(const u16* __restrict__ xz,
                                              const float* __restrict__ cw,
                                              const float* __restrict__ cb,
                                              float* __restrict__ uf,
                                              u16* __restrict__ uh) {
  int idx = blockIdx.x * 256 + threadIdx.x;        // ROWS*DI
  int c = idx & (DI - 1);
  int row = idx >> 10;
  int l = row & (L_ - 1);
  float acc = cb[c];
#pragma unroll
  for (int j = 0; j < 4; ++j) {
    int ls = l + j - 3;
    if (ls >= 0)
      acc += bf2f(xz[(size_t)(row + j - 3) * (2 * DI) + c]) * cw[c * 4 + j];
  }
  float s = acc * sigmoidf_(acc);
  uf[idx] = s;
  uh[idx] = f2bf(s);
}

// ---------------- dt = softplus(xdbl[:, :32] @ dtw^T + dtb) ----------------
__global__ __launch_bounds__(256) void dtproj_k(const float* __restrict__ xdbl,
                                                const float* __restrict__ dw,
                                                const float* __restrict__ db,
                                                float* __restrict__ dt) {
  int row0 = blockIdx.x * 4;
  int tid = threadIdx.x;
  __shared__ float xr[4 * DTR];
  if (tid < 128) xr[tid] = xdbl[(size_t)(row0 + (tid >> 5)) * 64 + (tid & 31)];
  __syncthreads();
#pragma unroll
  for (int q = 0; q < 4; ++q) {
    int c = q * 256 + tid;
    float wv[DTR];
    const float* wr_ = dw + (size_t)c * DTR;
#pragma unroll
    for (int k = 0; k < DTR; ++k) wv[k] = wr_[k];
    float bias = db[c];
#pragma unroll
    for (int r = 0; r < 4; ++r) {
      float a = bias;
#pragma unroll
      for (int k = 0; k < DTR; ++k) a += xr[r * DTR + k] * wv[k];
      float sp = (a > 20.f) ? a : log1pf(__expf(a));
      dt[(size_t)(row0 + r) * DI + c] = sp;
    }
  }
}

// ---------------- chunk-parallel selective scan ----------------
// pass 1: per (b, chunk, d, n) local scan from h=0 -> store decay-product + local end state
__global__ __launch_bounds__(256) void scan1_k(const float* __restrict__ u,
                                               const float* __restrict__ dt,
                                               const float* __restrict__ xdbl,
                                               const float* __restrict__ alog,
                                               float* __restrict__ chk) {
  int blk = blockIdx.x;                  // 4 * 32 * 64 = 8192 blocks
  int b = blk >> 11;
  int rem = blk & 2047;
  int c = rem >> 6;
  int d0 = (rem & 63) << 4;
  int tid = threadIdx.x;
  int n = tid & 15, d = d0 + (tid >> 4);
  float A = -__expf(alog[d * NST + n]);
  float h = 0.f, ap = 1.f;
  int t0 = c * CLEN;
  size_t rbase = ((size_t)b * L_ + t0) * DI + d;
  size_t xbase = ((size_t)b * L_ + t0) * 64;
  for (int t = 0; t < CLEN; ++t) {
    float dtv = dt[rbase];
    float uv = u[rbase];
    float bv = xdbl[xbase + DTR + n];
    float da = __expf(dtv * A);
    h = da * h + (dtv * uv) * bv;
    ap *= da;
    rbase += DI; xbase += 64;
  }
  size_t idx = ((size_t)(b * NCHUNK + c) * DI + d) * NST + n;
  const size_t H = (size_t)B_ * NCHUNK * DI * NST;
  chk[idx] = ap;
  chk[H + idx] = h;
}

// pass 2: per (b,d,n): sequential combine over chunks; overwrite chk_h with start states
__global__ __launch_bounds__(256) void scan2_k(float* __restrict__ chk) {
  int j = blockIdx.x * 256 + threadIdx.x;   // 65536 = B*DI*NST
  int n = j & 15;
  int d = (j >> 4) & (DI - 1);
  int b = j >> 14;
  const size_t H = (size_t)B_ * NCHUNK * DI * NST;
  float h = 0.f;
  for (int c = 0; c < NCHUNK; ++c) {
    size_t idx = ((size_t)(b * NCHUNK + c) * DI + d) * NST + n;
    float a = chk[idx];
    float hl = chk[H + idx];
    chk[H + idx] = h;               // start state for this chunk
    h = a * h + hl;
  }
}

// pass 3: re-run chunk from true start state, emit y (aliases u; read-before-write per t)
__global__ __launch_bounds__(256) void scan3_k(const float* u,
                                               const float* __restrict__ dt,
                                               const float* __restrict__ xdbl,
                                               const float* __restrict__ alog,
                                               const float* __restrict__ dvec,
                                               const float* __restrict__ chk,
                                               float* y) {
  int blk = blockIdx.x;                  // 8192 blocks
  int b = blk >> 11;
  int rem = blk & 2047;
  int c = rem >> 6;
  int d0 = (rem & 63) << 4;
  int tid = threadIdx.x;
  int n = tid & 15, d = d0 + (tid >> 4);
  float A = -__expf(alog[d * NST + n]);
  float Dv = dvec[d];
  size_t idx = ((size_t)(b * NCHUNK + c) * DI + d) * NST + n;
  const size_t H = (size_t)B_ * NCHUNK * DI * NST;
  float h = chk[H + idx];
  int t0 = c * CLEN;
  size_t rbase = ((size_t)b * L_ + t0) * DI + d;
  size_t xbase = ((size_t)b * L_ + t0) * 64;
  for (int t = 0; t < CLEN; ++t) {
    float dtv = dt[rbase];
    float uv = u[rbase];
    float bv = xdbl[xbase + DTR + n];
    float cv = xdbl[xbase + DTR + NST + n];
    h = __expf(dtv * A) * h + (dtv * uv) * bv;
    float p = h * cv;
    p += __shfl_xor(p, 1);
    p += __shfl_xor(p, 2);
    p += __shfl_xor(p, 4);
    p += __shfl_xor(p, 8);
    if (n == 0) y[rbase] = p + uv * Dv;
    rbase += DI; xbase += 64;
  }
}

// ---------------- gate: yg = y * silu(z) (bf16 out) ----------------
__global__ __launch_bounds__(256) void gate_k(const float* __restrict__ y,
                                              const u16* __restrict__ xz,
                                              u16* __restrict__ yg) {
  int idx = blockIdx.x * 256 + threadIdx.x;        // ROWS*DI
  int c = idx & (DI - 1);
  int row = idx >> 10;
  float z = bf2f(xz[(size_t)row * (2 * DI) + DI + c]);
  yg[idx] = f2bf(y[idx] * z * sigmoidf_(z));
}

// ---------------- final rmsnorm(hid+res) -> concat buffer (with flip for dir 1) ----------------
__global__ __launch_bounds__(256) void fincat_k(const float* __restrict__ hid,
                                                const float* __restrict__ res,
                                                const float* __restrict__ w,
                                                u16* __restrict__ cat, int dir) {
  int row = blockIdx.x;
  int tid = threadIdx.x;
  int base = row * DM;
  float x0 = hid[base + tid] + res[base + tid];
  float x1 = hid[base + 256 + tid] + res[base + 256 + tid];
  float s = x0 * x0 + x1 * x1;
  for (int off = 32; off; off >>= 1) s += __shfl_xor(s, off);
  __shared__ float ps[4];
  if (!(tid & 63)) ps[tid >> 6] = s;
  __syncthreads();
  float tot = ps[0] + ps[1] + ps[2] + ps[3];
  float rs = 1.f / sqrtf(tot / (float)DM + 1e-5f);
  int b = row >> 11, l = row & (L_ - 1);
  size_t drow = dir ? ((size_t)(b << 11) + (L_ - 1 - l)) : (size_t)row;
  size_t obase = drow * (2 * DM) + (size_t)dir * DM;
  cat[obase + tid]       = f2bf(x0 * rs * w[tid]);
  cat[obase + 256 + tid] = f2bf(x1 * rs * w[tid + 256]);
}

extern "C" void kernel_launch(void* const* d_in, const int* in_sizes, int n_in,
                              void* d_out, int out_size, void* d_ws, size_t ws_size,
                              hipStream_t stream) {
  const int*   ids      = (const int*)d_in[0];
  const float* embed    = (const float*)d_in[2];
  const float* in_w     = (const float*)d_in[3];
  const float* conv_w   = (const float*)d_in[4];
  const float* conv_b   = (const float*)d_in[5];
  const float* x_w      = (const float*)d_in[6];
  const float* dt_w     = (const float*)d_in[7];
  const float* dt_bias  = (const float*)d_in[8];
  const float* A_log    = (const float*)d_in[9];
  const float* Dp       = (const float*)d_in[10];
  const float* out_w    = (const float*)d_in[11];
  const float* norm_w   = (const float*)d_in[12];
  const float* norm_f   = (const float*)d_in[13];
  const float* proj_w   = (const float*)d_in[14];
  const float* proj_b   = (const float*)d_in[15];

  char* ws = (char*)d_ws;
  size_t off = 0;
  auto alloc = [&](size_t bytes) {
    void* p = ws + off;
    off += (bytes + 255) & ~(size_t)255;
    return p;
  };
  float* res  = (float*)alloc((size_t)ROWS * DM * 4);        // 16.8 MB
  float* hid  = (float*)alloc((size_t)ROWS * DM * 4);        // 16.8 MB
  u16*   xnyg = (u16*)alloc((size_t)ROWS * DI * 2);          // 16.8 MB (xn | yg)
  u16*   xz   = (u16*)alloc((size_t)ROWS * 2 * DI * 2);      // 33.6 MB
  float* u_f  = (float*)alloc((size_t)ROWS * DI * 4);        // 33.6 MB (y aliases)
  u16*   u_h  = (u16*)alloc((size_t)ROWS * DI * 2);          // 16.8 MB (chk aliases)
  float* xdbl = (float*)alloc((size_t)ROWS * 64 * 4);        //  2.1 MB
  float* dtf  = (float*)alloc((size_t)ROWS * DI * 4);        // 33.6 MB
  u16*   cat  = (u16*)alloc((size_t)ROWS * 2 * DM * 2);      // 16.8 MB
  const int N_IN  = 4 * 2 * DI * DM;   // 4,194,304
  const int N_XW  = 4 * 64 * DI;       //   262,144
  const int N_OW  = 4 * DM * DI;       // 2,097,152
  const int N_PW  = DM * 2 * DM;       //   524,288
  u16* in_wb  = (u16*)alloc((size_t)N_IN * 2);               //  8.4 MB
  u16* x_wb   = (u16*)alloc((size_t)N_XW * 2);               //  0.5 MB
  u16* out_wb = (u16*)alloc((size_t)N_OW * 2);               //  4.2 MB
  u16* pr_wb  = (u16*)alloc((size_t)N_PW * 2);               //  1.0 MB
  if (off > ws_size) return;

  // chk (2 * B*NCHUNK*DI*NST floats = 16.78 MB) aliases u_h, which is dead
  // after the x_proj GEMM and rewritten by next layer's conv_k.
  float* chk = (float*)u_h;

  cvt_k<<<(N_IN / 4 + 255) / 256, 256, 0, stream>>>(in_w, in_wb, N_IN / 4);
  cvt_k<<<(N_XW / 4 + 255) / 256, 256, 0, stream>>>(x_w, x_wb, N_XW / 4);
  cvt_k<<<(N_OW / 4 + 255) / 256, 256, 0, stream>>>(out_w, out_wb, N_OW / 4);
  cvt_k<<<(N_PW / 4 + 255) / 256, 256, 0, stream>>>(proj_w, pr_wb, N_PW / 4);

  for (int d = 0; d < 2; ++d) {
    embed_k<<<ROWS * DM / 256, 256, 0, stream>>>(ids, embed + (size_t)d * 128 * DM, res, d);
    for (int i = 0; i < 2; ++i) {
      int li = d * 2 + i;
      if (i == 0)
        addnorm_k<false><<<ROWS, 256, 0, stream>>>(res, hid, norm_w + (size_t)li * DM, xnyg);
      else
        addnorm_k<true><<<ROWS, 256, 0, stream>>>(res, hid, norm_w + (size_t)li * DM, xnyg);
      gemm_bt<128, true, false><<<dim3(ROWS / 128, 2 * DI / 128), 256, 0, stream>>>(
          xnyg, in_wb + (size_t)li * 2 * DI * DM, xz, nullptr, 2 * DI, DM);
      conv_k<<<ROWS * DI / 256, 256, 0, stream>>>(
          xz, conv_w + (size_t)li * DI * 4, conv_b + (size_t)li * DI, u_f, u_h);
      gemm_bt<64, false, false><<<dim3(ROWS / 128, 1), 256, 0, stream>>>(
          u_h, x_wb + (size_t)li * 64 * DI, xdbl, nullptr, 64, DI);
      dtproj_k<<<ROWS / 4, 256, 0, stream>>>(
          xdbl, dt_w + (size_t)li * DI * DTR, dt_bias + (size_t)li * DI, dtf);
      scan1_k<<<B_ * NCHUNK * (DI / 16), 256, 0, stream>>>(
          u_f, dtf, xdbl, A_log + (size_t)li * DI * NST, chk);
      scan2_k<<<(B_ * DI * NST) / 256, 256, 0, stream>>>(chk);
      scan3_k<<<B_ * NCHUNK * (DI / 16), 256, 0, stream>>>(
          u_f, dtf, xdbl, A_log + (size_t)li * DI * NST, Dp + (size_t)li * DI, chk, u_f);
      gate_k<<<ROWS * DI / 256, 256, 0, stream>>>(u_f, xz, xnyg);
      gemm_bt<128, false, false><<<dim3(ROWS / 128, DM / 128), 256, 0, stream>>>(
          xnyg, out_wb + (size_t)li * DM * DI, hid, nullptr, DM, DI);
    }
    fincat_k<<<ROWS, 256, 0, stream>>>(hid, res, norm_f + (size_t)d * DM, cat, d);
  }
  gemm_bt<128, false, true><<<dim3(ROWS / 128, DM / 128), 256, 0, stream>>>(
      cat, pr_wb, (float*)d_out, proj_b, DM, DI);
}

// Round 4
// 1110.842 us; speedup vs baseline: 4.0440x; 1.3897x over previous
//
#include <hip/hip_runtime.h>
#include <hip/hip_bf16.h>

#define B_   4
#define L_   2048
#define DM   512
#define DI   1024
#define NST  16
#define DTR  32
#define ROWS (B_ * L_)   // 8192
#define NCHUNK 32
#define CLEN  (L_ / NCHUNK)   // 64

typedef unsigned short u16;
typedef __attribute__((ext_vector_type(8))) short bf16x8;
typedef __attribute__((ext_vector_type(4))) float f32x4;
typedef __attribute__((ext_vector_type(4))) float float4v;

__device__ __forceinline__ float bf2f(u16 h) {
  union { unsigned int u; float f; } v; v.u = ((unsigned int)h) << 16; return v.f;
}
__device__ __forceinline__ u16 f2bf(float f) {
  union { float f; unsigned int u; } v; v.f = f;
  unsigned int u = v.u;
  if ((u & 0x7fffffffu) > 0x7f800000u) return (u16)((u >> 16) | 0x0040u);
  return (u16)((u + 0x7fffu + ((u >> 16) & 1u)) >> 16);
}
__device__ __forceinline__ float sigmoidf_(float x) { return 1.f / (1.f + __expf(-x)); }

// ---------------- f32 -> bf16 weight conversion ----------------
__global__ __launch_bounds__(256) void cvt_k(const float* __restrict__ in,
                                             u16* __restrict__ out, int n4) {
  int i = blockIdx.x * 256 + threadIdx.x;       // n4 = n/4
  if (i >= n4) return;
  float4v v = *(const float4v*)&in[i * 4];
  u16 o[4];
  o[0] = f2bf(v.x); o[1] = f2bf(v.y); o[2] = f2bf(v.z); o[3] = f2bf(v.w);
  *(ulong1*)&out[i * 4] = *(ulong1*)o;
}

// ---------------- embed gather (writes f32 residual) ----------------
__global__ __launch_bounds__(256) void embed_k(const int* __restrict__ ids,
                                               const float* __restrict__ emb,
                                               float* __restrict__ res, int flip) {
  int idx = blockIdx.x * 256 + threadIdx.x;         // ROWS*DM threads
  int c = idx & (DM - 1);
  int row = idx >> 9;
  int b = row >> 11;
  int l = row & (L_ - 1);
  int sl = flip ? (L_ - 1 - l) : l;
  int id = ids[(b << 11) + sl];
  res[idx] = emb[id * DM + c];
}

// ---------------- (res += hid); xn = rmsnorm(res) * w  (bf16 out) ----------------
template <bool ADD>
__global__ __launch_bounds__(256) void addnorm_k(float* __restrict__ res,
                                                 const float* __restrict__ hid,
                                                 const float* __restrict__ w,
                                                 u16* __restrict__ xn) {
  int row = blockIdx.x;
  int tid = threadIdx.x;
  int base = row * DM;
  float x0 = res[base + tid];
  float x1 = res[base + 256 + tid];
  if (ADD) {
    x0 += hid[base + tid];
    x1 += hid[base + 256 + tid];
    res[base + tid] = x0;
    res[base + 256 + tid] = x1;
  }
  float s = x0 * x0 + x1 * x1;
  for (int off = 32; off; off >>= 1) s += __shfl_xor(s, off);
  __shared__ float ps[4];
  if (!(tid & 63)) ps[tid >> 6] = s;
  __syncthreads();
  float tot = ps[0] + ps[1] + ps[2] + ps[3];
  float rs = 1.f / sqrtf(tot / (float)DM + 1e-5f);
  xn[base + tid]       = f2bf(x0 * rs * w[tid]);
  xn[base + 256 + tid] = f2bf(x1 * rs * w[tid + 256]);
}

// ---------------- GEMM: out[m][n] = sum_k A[m][k] * W[n][k] ----------------
template <int BN, bool OUT_BF16, bool HAS_BIAS>
__global__ __launch_bounds__(256) void gemm_bt(const u16* __restrict__ A,
                                               const u16* __restrict__ W,
                                               void* __restrict__ outp,
                                               const float* __restrict__ bias,
                                               int N, int K) {
  constexpr int BM = 128, BK = 32, LDT = BK + 8;   // +8 bf16 pad -> 80B row stride
  constexpr int NF = BN / 32;                      // n-frags per wave
  __shared__ u16 As[BM * LDT];
  __shared__ u16 Wsh[BN * LDT];
  int tid = threadIdx.x;
  int lane = tid & 63;
  int wv = tid >> 6;
  int wr = wv >> 1, wc = wv & 1;
  int m0 = blockIdx.x * BM, n0 = blockIdx.y * BN;
  f32x4 acc[4][NF];
#pragma unroll
  for (int i = 0; i < 4; ++i)
#pragma unroll
    for (int j = 0; j < NF; ++j) acc[i][j] = (f32x4){0.f, 0.f, 0.f, 0.f};
  int rr = lane & 15;
  int kk = (lane >> 4) << 3;
  for (int k0 = 0; k0 < K; k0 += BK) {
#pragma unroll
    for (int p = 0; p < (BM * BK) / 2048; ++p) {
      int idx = p * 2048 + tid * 8;
      int r = idx >> 5, c = idx & 31;
      *(bf16x8*)&As[r * LDT + c] = *(const bf16x8*)&A[(size_t)(m0 + r) * K + k0 + c];
    }
#pragma unroll
    for (int p = 0; p < (BN * BK) / 2048; ++p) {
      int idx = p * 2048 + tid * 8;
      int r = idx >> 5, c = idx & 31;
      *(bf16x8*)&Wsh[r * LDT + c] = *(const bf16x8*)&W[(size_t)(n0 + r) * K + k0 + c];
    }
    __syncthreads();
    bf16x8 af[4], wf[NF];
#pragma unroll
    for (int mi = 0; mi < 4; ++mi)
      af[mi] = *(bf16x8*)&As[(wr * 64 + mi * 16 + rr) * LDT + kk];
#pragma unroll
    for (int ni = 0; ni < NF; ++ni)
      wf[ni] = *(bf16x8*)&Wsh[(wc * (BN / 2) + ni * 16 + rr) * LDT + kk];
#pragma unroll
    for (int mi = 0; mi < 4; ++mi)
#pragma unroll
      for (int ni = 0; ni < NF; ++ni)
        acc[mi][ni] = __builtin_amdgcn_mfma_f32_16x16x32_bf16(af[mi], wf[ni], acc[mi][ni], 0, 0, 0);
    __syncthreads();
  }
  // C/D layout: col = lane&15, row = (lane>>4)*4 + j
  int cr = (lane >> 4) << 2;
  int cc = lane & 15;
#pragma unroll
  for (int mi = 0; mi < 4; ++mi)
#pragma unroll
    for (int ni = 0; ni < NF; ++ni) {
      int row = m0 + wr * 64 + mi * 16 + cr;
      int col = n0 + wc * (BN / 2) + ni * 16 + cc;
      float bv = HAS_BIAS ? bias[col] : 0.f;
#pragma unroll
      for (int j = 0; j < 4; ++j) {
        float v = acc[mi][ni][j] + bv;
        if (OUT_BF16)
          ((u16*)outp)[(size_t)(row + j) * N + col] = f2bf(v);
        else
          ((float*)outp)[(size_t)(row + j) * N + col] = v;
      }
    }
}

// ---------------- depthwise causal conv (k=4) + bias + SiLU ----------------
__global__ __launch_bounds__(256) void conv_k(const u16* __restrict__ xz,
                                              const float* __restrict__ cw,
                                              const float* __restrict__ cb,
                                              float* __restrict__ uf,
                                              u16* __restrict__ uh) {
  int idx = blockIdx.x * 256 + threadIdx.x;        // ROWS*DI
  int c = idx & (DI - 1);
  int row = idx >> 10;
  int l = row & (L_ - 1);
  float acc = cb[c];
#pragma unroll
  for (int j = 0; j < 4; ++j) {
    int ls = l + j - 3;
    if (ls >= 0)
      acc += bf2f(xz[(size_t)(row + j - 3) * (2 * DI) + c]) * cw[c * 4 + j];
  }
  float s = acc * sigmoidf_(acc);
  uf[idx] = s;
  uh[idx] = f2bf(s);
}

// ---------------- dt = softplus(xdbl[:, :32] @ dtw^T + dtb) ----------------
__global__ __launch_bounds__(256) void dtproj_k(const float* __restrict__ xdbl,
                                                const float* __restrict__ dw,
                                                const float* __restrict__ db,
                                                float* __restrict__ dt) {
  int row0 = blockIdx.x * 4;
  int tid = threadIdx.x;
  __shared__ float xr[4 * DTR];
  if (tid < 128) xr[tid] = xdbl[(size_t)(row0 + (tid >> 5)) * 64 + (tid & 31)];
  __syncthreads();
#pragma unroll
  for (int q = 0; q < 4; ++q) {
    int c = q * 256 + tid;
    float wv[DTR];
    const float* wr_ = dw + (size_t)c * DTR;
#pragma unroll
    for (int k = 0; k < DTR; ++k) wv[k] = wr_[k];
    float bias = db[c];
#pragma unroll
    for (int r = 0; r < 4; ++r) {
      float a = bias;
#pragma unroll
      for (int k = 0; k < DTR; ++k) a += xr[r * DTR + k] * wv[k];
      float sp = (a > 20.f) ? a : log1pf(__expf(a));
      dt[(size_t)(row0 + r) * DI + c] = sp;
    }
  }
}

// ---------------- chunk-parallel selective scan (1 thread = 1 channel, 16 states in regs) ----
// pass 1: local scan from h=0 over chunk -> store decay exp(A*S) + local end state
__global__ __launch_bounds__(256) void scan1_k(const float* __restrict__ u,
                                               const float* __restrict__ dt,
                                               const float* __restrict__ xdbl,
                                               const float* __restrict__ alog,
                                               float* __restrict__ chk) {
  int blk = blockIdx.x;            // B*NCHUNK*(DI/256) = 4*32*4 = 512
  int db = blk & 3;
  int c  = (blk >> 2) & (NCHUNK - 1);
  int b  = blk >> 7;
  int d  = db * 256 + threadIdx.x;
  float A[NST], h[NST];
#pragma unroll
  for (int n = 0; n < NST; ++n) {
    A[n] = -__expf(alog[d * NST + n]);
    h[n] = 0.f;
  }
  float S = 0.f;
  int t0 = c * CLEN;
  size_t rbase = ((size_t)b * L_ + t0) * DI + d;
  size_t xbase = ((size_t)b * L_ + t0) * 64;
  for (int t = 0; t < CLEN; ++t) {
    float dtv = dt[rbase];
    float du  = dtv * u[rbase];
    S += dtv;
#pragma unroll
    for (int n = 0; n < NST; ++n) {
      float bv = xdbl[xbase + DTR + n];
      h[n] = __expf(dtv * A[n]) * h[n] + du * bv;
    }
    rbase += DI; xbase += 64;
  }
  const size_t H = (size_t)B_ * NCHUNK * DI * NST;
  size_t idx = ((size_t)(b * NCHUNK + c) * DI + d) * NST;
#pragma unroll
  for (int n = 0; n < NST; ++n) {
    chk[idx + n]     = __expf(A[n] * S);
    chk[H + idx + n] = h[n];
  }
}

// pass 2: per (b,d,n): sequential combine over chunks; overwrite chk_h with start states
__global__ __launch_bounds__(256) void scan2_k(float* __restrict__ chk) {
  int j = blockIdx.x * 256 + threadIdx.x;   // 65536 = B*DI*NST
  int n = j & 15;
  int d = (j >> 4) & (DI - 1);
  int b = j >> 14;
  const size_t H = (size_t)B_ * NCHUNK * DI * NST;
  float h = 0.f;
  for (int c = 0; c < NCHUNK; ++c) {
    size_t idx = ((size_t)(b * NCHUNK + c) * DI + d) * NST + n;
    float a = chk[idx];
    float hl = chk[H + idx];
    chk[H + idx] = h;               // start state for this chunk
    h = a * h + hl;
  }
}

// pass 3: re-run chunk from true start state; fused gate -> bf16 yg
__global__ __launch_bounds__(256) void scan3_k(const float* __restrict__ u,
                                               const float* __restrict__ dt,
                                               const float* __restrict__ xdbl,
                                               const float* __restrict__ alog,
                                               const float* __restrict__ dvec,
                                               const float* __restrict__ chk,
                                               const u16* __restrict__ xz,
                                               u16* __restrict__ yg) {
  int blk = blockIdx.x;            // 512
  int db = blk & 3;
  int c  = (blk >> 2) & (NCHUNK - 1);
  int b  = blk >> 7;
  int d  = db * 256 + threadIdx.x;
  const size_t H = (size_t)B_ * NCHUNK * DI * NST;
  size_t cidx = ((size_t)(b * NCHUNK + c) * DI + d) * NST;
  float A[NST], h[NST];
#pragma unroll
  for (int n = 0; n < NST; ++n) {
    A[n] = -__expf(alog[d * NST + n]);
    h[n] = chk[H + cidx + n];
  }
  float Dv = dvec[d];
  int t0 = c * CLEN;
  size_t rbase = ((size_t)b * L_ + t0) * DI + d;
  size_t xbase = ((size_t)b * L_ + t0) * 64;
  size_t zbase = ((size_t)b * L_ + t0) * (2 * DI) + DI + d;
  for (int t = 0; t < CLEN; ++t) {
    float dtv = dt[rbase];
    float uv  = u[rbase];
    float du  = dtv * uv;
    float acc = 0.f;
#pragma unroll
    for (int n = 0; n < NST; ++n) {
      float bv = xdbl[xbase + DTR + n];
      float cv = xdbl[xbase + DTR + NST + n];
      h[n] = __expf(dtv * A[n]) * h[n] + du * bv;
      acc += h[n] * cv;
    }
    float y = acc + uv * Dv;
    float z = bf2f(xz[zbase]);
    yg[rbase] = f2bf(y * z * sigmoidf_(z));
    rbase += DI; xbase += 64; zbase += 2 * DI;
  }
}

// ---------------- final rmsnorm(hid+res) -> concat buffer (with flip for dir 1) ----------------
__global__ __launch_bounds__(256) void fincat_k(const float* __restrict__ hid,
                                                const float* __restrict__ res,
                                                const float* __restrict__ w,
                                                u16* __restrict__ cat, int dir) {
  int row = blockIdx.x;
  int tid = threadIdx.x;
  int base = row * DM;
  float x0 = hid[base + tid] + res[base + tid];
  float x1 = hid[base + 256 + tid] + res[base + 256 + tid];
  float s = x0 * x0 + x1 * x1;
  for (int off = 32; off; off >>= 1) s += __shfl_xor(s, off);
  __shared__ float ps[4];
  if (!(tid & 63)) ps[tid >> 6] = s;
  __syncthreads();
  float tot = ps[0] + ps[1] + ps[2] + ps[3];
  float rs = 1.f / sqrtf(tot / (float)DM + 1e-5f);
  int b = row >> 11, l = row & (L_ - 1);
  size_t drow = dir ? ((size_t)(b << 11) + (L_ - 1 - l)) : (size_t)row;
  size_t obase = drow * (2 * DM) + (size_t)dir * DM;
  cat[obase + tid]       = f2bf(x0 * rs * w[tid]);
  cat[obase + 256 + tid] = f2bf(x1 * rs * w[tid + 256]);
}

extern "C" void kernel_launch(void* const* d_in, const int* in_sizes, int n_in,
                              void* d_out, int out_size, void* d_ws, size_t ws_size,
                              hipStream_t stream) {
  const int*   ids      = (const int*)d_in[0];
  const float* embed    = (const float*)d_in[2];
  const float* in_w     = (const float*)d_in[3];
  const float* conv_w   = (const float*)d_in[4];
  const float* conv_b   = (const float*)d_in[5];
  const float* x_w      = (const float*)d_in[6];
  const float* dt_w     = (const float*)d_in[7];
  const float* dt_bias  = (const float*)d_in[8];
  const float* A_log    = (const float*)d_in[9];
  const float* Dp       = (const float*)d_in[10];
  const float* out_w    = (const float*)d_in[11];
  const float* norm_w   = (const float*)d_in[12];
  const float* norm_f   = (const float*)d_in[13];
  const float* proj_w   = (const float*)d_in[14];
  const float* proj_b   = (const float*)d_in[15];

  char* ws = (char*)d_ws;
  size_t off = 0;
  auto alloc = [&](size_t bytes) {
    void* p = ws + off;
    off += (bytes + 255) & ~(size_t)255;
    return p;
  };
  float* res  = (float*)alloc((size_t)ROWS * DM * 4);        // 16.8 MB
  float* hid  = (float*)alloc((size_t)ROWS * DM * 4);        // 16.8 MB
  u16*   xnyg = (u16*)alloc((size_t)ROWS * DI * 2);          // 16.8 MB (xn | yg)
  u16*   xz   = (u16*)alloc((size_t)ROWS * 2 * DI * 2);      // 33.6 MB
  float* u_f  = (float*)alloc((size_t)ROWS * DI * 4);        // 33.6 MB
  u16*   u_h  = (u16*)alloc((size_t)ROWS * DI * 2);          // 16.8 MB (chk aliases)
  float* xdbl = (float*)alloc((size_t)ROWS * 64 * 4);        //  2.1 MB
  float* dtf  = (float*)alloc((size_t)ROWS * DI * 4);        // 33.6 MB
  u16*   cat  = (u16*)alloc((size_t)ROWS * 2 * DM * 2);      // 16.8 MB
  const int N_IN  = 4 * 2 * DI * DM;   // 4,194,304
  const int N_XW  = 4 * 64 * DI;       //   262,144
  const int N_OW  = 4 * DM * DI;       // 2,097,152
  const int N_PW  = DM * 2 * DM;       //   524,288
  u16* in_wb  = (u16*)alloc((size_t)N_IN * 2);               //  8.4 MB
  u16* x_wb   = (u16*)alloc((size_t)N_XW * 2);               //  0.5 MB
  u16* out_wb = (u16*)alloc((size_t)N_OW * 2);               //  4.2 MB
  u16* pr_wb  = (u16*)alloc((size_t)N_PW * 2);               //  1.0 MB
  if (off > ws_size) return;

  // chk (2 * B*NCHUNK*DI*NST floats = 16.78 MB) aliases u_h, dead after x_proj GEMM.
  float* chk = (float*)u_h;

  cvt_k<<<(N_IN / 4 + 255) / 256, 256, 0, stream>>>(in_w, in_wb, N_IN / 4);
  cvt_k<<<(N_XW / 4 + 255) / 256, 256, 0, stream>>>(x_w, x_wb, N_XW / 4);
  cvt_k<<<(N_OW / 4 + 255) / 256, 256, 0, stream>>>(out_w, out_wb, N_OW / 4);
  cvt_k<<<(N_PW / 4 + 255) / 256, 256, 0, stream>>>(proj_w, pr_wb, N_PW / 4);

  for (int d = 0; d < 2; ++d) {
    embed_k<<<ROWS * DM / 256, 256, 0, stream>>>(ids, embed + (size_t)d * 128 * DM, res, d);
    for (int i = 0; i < 2; ++i) {
      int li = d * 2 + i;
      if (i == 0)
        addnorm_k<false><<<ROWS, 256, 0, stream>>>(res, hid, norm_w + (size_t)li * DM, xnyg);
      else
        addnorm_k<true><<<ROWS, 256, 0, stream>>>(res, hid, norm_w + (size_t)li * DM, xnyg);
      gemm_bt<128, true, false><<<dim3(ROWS / 128, 2 * DI / 128), 256, 0, stream>>>(
          xnyg, in_wb + (size_t)li * 2 * DI * DM, xz, nullptr, 2 * DI, DM);
      conv_k<<<ROWS * DI / 256, 256, 0, stream>>>(
          xz, conv_w + (size_t)li * DI * 4, conv_b + (size_t)li * DI, u_f, u_h);
      gemm_bt<64, false, false><<<dim3(ROWS / 128, 1), 256, 0, stream>>>(
          u_h, x_wb + (size_t)li * 64 * DI, xdbl, nullptr, 64, DI);
      dtproj_k<<<ROWS / 4, 256, 0, stream>>>(
          xdbl, dt_w + (size_t)li * DI * DTR, dt_bias + (size_t)li * DI, dtf);
      scan1_k<<<B_ * NCHUNK * (DI / 256), 256, 0, stream>>>(
          u_f, dtf, xdbl, A_log + (size_t)li * DI * NST, chk);
      scan2_k<<<(B_ * DI * NST) / 256, 256, 0, stream>>>(chk);
      scan3_k<<<B_ * NCHUNK * (DI / 256), 256, 0, stream>>>(
          u_f, dtf, xdbl, A_log + (size_t)li * DI * NST, Dp + (size_t)li * DI, chk,
          xz, xnyg);
      gemm_bt<128, false, false><<<dim3(ROWS / 128, DM / 128), 256, 0, stream>>>(
          xnyg, out_wb + (size_t)li * DM * DI, hid, nullptr, DM, DI);
    }
    fincat_k<<<ROWS, 256, 0, stream>>>(hid, res, norm_f + (size_t)d * DM, cat, d);
  }
  gemm_bt<128, false, true><<<dim3(ROWS / 128, DM / 128), 256, 0, stream>>>(
      cat, pr_wb, (float*)d_out, proj_b, DM, DI);
}